// Round 1
// baseline (263.866 us; speedup 1.0000x reference)
//
#include <hip/hip_runtime.h>

// TNorm: out[b] = outer(g0, g1, g2, g3) flattened, g = x[b].reshape(4, 8).
// B=16384 rows, 32 inputs/row, 4096 outputs/row (fp32).
// Streaming floor: 256 MiB out + 2 MiB in -> ~41 us at the 6.6 TB/s the
// harness fill itself achieves.
//
// R1/R2 history: 1 row/block = 256 us, 8 rows/block = 254 us -> dur_us has a
// ~161 us additive harness term (poison fills dominate the rocprof top-5;
// the kernel dispatch itself is < 161 us, inferred ~93 us).
// R3 (this): non-temporal dwordx4 stores. Regular stores write-allocate in
// L2/L3 and evict the 1 GiB of dirty poison lines during our window (~2x
// write traffic). `nt` streams past the caches. Also hoist per-thread
// invariant LDS reads: for element e = 4t + 1024i,
//   j = ((t>>7) + 2i) & 7  (varies with i)
//   k = (t>>4) & 7, l = (t>>1) & 7, g3-half = t & 1   (invariant in i, r-indep)

#define ROW_IN 32
#define ROW_OUT 4096
#define ROWS_PER_BLOCK 8

typedef float f4 __attribute__((ext_vector_type(4)));

__global__ __launch_bounds__(256) void TNorm_71038759076547_kernel(
    const float* __restrict__ x, float* __restrict__ out) {
    __shared__ float g[ROWS_PER_BLOCK * ROW_IN];  // 1 KB

    const int t = threadIdx.x;
    const size_t row0 = (size_t)blockIdx.x * ROWS_PER_BLOCK;

    // Stage 8 rows (256 floats) with 64 float4 loads.
    if (t < ROWS_PER_BLOCK * (ROW_IN / 4)) {
        ((f4*)g)[t] = ((const f4*)(x + row0 * ROW_IN))[t];
    }
    __syncthreads();

    // Per-thread invariants (see header comment).
    const int kk   = (t >> 4) & 7;
    const int ll   = (t >> 1) & 7;
    const int half = t & 1;          // which g3 float4 half
    const int jb   = (t >> 7) & 7;   // j base; j = (jb + 2i) & 7

    f4* outbase = (f4*)out + row0 * (ROW_OUT / 4);

#pragma unroll
    for (int r = 0; r < ROWS_PER_BLOCK; ++r) {
        const float* gr = g + r * ROW_IN;
        const float c12 = gr[8 + kk] * gr[16 + ll];      // g1[k] * g2[l]
        const f4 gm = *(const f4*)(gr + 24 + 4 * half);  // g3 half (16B aligned)

        f4* out4 = outbase + r * (ROW_OUT / 4);

#pragma unroll
        for (int i = 0; i < 4; ++i) {
            const int j = (jb + 2 * i) & 7;
            const float s = gr[j] * c12;                 // g0[j]*g1[k]*g2[l]
            f4 r4 = gm * s;
            __builtin_nontemporal_store(r4, out4 + t + 256 * i);
        }
    }
}

extern "C" void kernel_launch(void* const* d_in, const int* in_sizes, int n_in,
                              void* d_out, int out_size, void* d_ws, size_t ws_size,
                              hipStream_t stream) {
    const float* x = (const float*)d_in[0];
    float* out = (float*)d_out;
    const int rows = in_sizes[0] / ROW_IN;            // 16384
    const int blocks = rows / ROWS_PER_BLOCK;         // 2048
    TNorm_71038759076547_kernel<<<blocks, 256, 0, stream>>>(x, out);
}